// Round 1
// baseline (717.187 us; speedup 1.0000x reference)
//
#include <hip/hip_runtime.h>
#include <cstdint>

#define NROWS 32768
#define HD    1024
#define KSEL  8192
#define LN_EPS 1e-12f
#define PD_EPS 1e-6f

typedef unsigned short u16;
typedef __bf16 bf16x8 __attribute__((ext_vector_type(8)));
typedef float  f32x4  __attribute__((ext_vector_type(4)));

__device__ inline u16 f2bf(float f) {
    union { float f; uint32_t u; } x; x.f = f;
    uint32_t r = (x.u + 0x7fffu + ((x.u >> 16) & 1u)) >> 16;
    return (u16)r;
}

__device__ inline uint2 pack4(float a, float b, float c, float d) {
    uint2 r;
    r.x = (uint32_t)f2bf(a) | ((uint32_t)f2bf(b) << 16);
    r.y = (uint32_t)f2bf(c) | ((uint32_t)f2bf(d) << 16);
    return r;
}

// ---------------- mask compaction (layout-robust) ----------------
__global__ void compact_mask_k(const uint8_t* mb, const int32_t* mi, int* idx) {
    __shared__ int cnt[1024];
    __shared__ int tmp[1024];
    __shared__ int mode_s;
    const int t = threadIdx.x;
    const int per = NROWS / 1024;      // 32
    const int base = t * per;
    int c0 = 0;
    for (int i = 0; i < per; ++i) c0 += (mb[base + i] != 0);
    tmp[t] = c0;
    __syncthreads();
    for (int off = 512; off > 0; off >>= 1) {
        if (t < off) tmp[t] += tmp[t + off];
        __syncthreads();
    }
    if (t == 0) mode_s = (tmp[0] == KSEL) ? 0 : 1;
    __syncthreads();
    const int mode = mode_s;
    int c = c0;
    if (mode) { c = 0; for (int i = 0; i < per; ++i) c += (mi[base + i] != 0); }
    cnt[t] = c;
    __syncthreads();
    // inclusive scan
    for (int off = 1; off < 1024; off <<= 1) {
        int add = (t >= off) ? cnt[t - off] : 0;
        __syncthreads();
        cnt[t] += add;
        __syncthreads();
    }
    int pos = cnt[t] - c;
    for (int i = 0; i < per; ++i) {
        bool v = mode ? (mi[base + i] != 0) : (mb[base + i] != 0);
        if (v) idx[pos++] = base + i;
    }
}

// ---------------- dense_w -> bf16 ----------------
__global__ void convert_w_k(const float* __restrict__ W, u16* __restrict__ Wb) {
    int i = (blockIdx.x * 256 + threadIdx.x) * 4;
    float4 v = *(const float4*)(W + i);
    *(uint2*)(Wb + i) = pack4(v.x, v.y, v.z, v.w);
}

// ---------------- gather selected rows -> bf16 ----------------
__global__ void gather_k(const float* __restrict__ msp, const float* __restrict__ lab,
                         const int* __restrict__ idx,
                         u16* __restrict__ predsB, u16* __restrict__ labelsB) {
    const int r = blockIdx.x;
    const int src = idx[r];
    const int t = threadIdx.x;
    float4 p = *(const float4*)(msp + (size_t)src * HD + t * 4);
    float4 q = *(const float4*)(lab + (size_t)src * HD + t * 4);
    *(uint2*)(predsB  + (size_t)r * HD + t * 4) = pack4(p.x, p.y, p.z, p.w);
    *(uint2*)(labelsB + (size_t)r * HD + t * 4) = pack4(q.x, q.y, q.z, q.w);
}

// ---------------- bf16 NT GEMM: C[M,N] = A[M,Kd] * Bt[N,Kd]^T ----------------
__global__ __launch_bounds__(256)
void gemm_nt_bf16(const u16* __restrict__ A, const u16* __restrict__ Bt,
                  float* __restrict__ C, int M, int N, int Kd) {
    __shared__ u16 As[128 * 32];
    __shared__ u16 Bs[128 * 32];
    const int nx  = N >> 7;
    const int nwg = (M >> 7) * nx;
    int bid = blockIdx.x;
    int wg  = ((nwg & 7) == 0) ? ((bid & 7) * (nwg >> 3) + (bid >> 3)) : bid;
    const int bm = wg / nx, bn = wg % nx;

    const int tid = threadIdx.x;
    const int l = tid & 63;
    const int w = tid >> 6;
    const int wr = w >> 1, wc = w & 1;
    const size_t brow = (size_t)bm * 128, bcol = (size_t)bn * 128;

    f32x4 acc[4][4] = {};

    const int lrow = l & 15, lk = (l >> 4) * 8;
    const int c0 = tid, c1 = tid + 256;
    const int ar0 = c0 >> 2, ak0 = (c0 & 3) * 8;
    const int ar1 = c1 >> 2, ak1 = (c1 & 3) * 8;

    for (int kt = 0; kt < Kd; kt += 32) {
        const u16* ga0 = A  + (brow + ar0) * Kd + kt + ak0;
        const u16* ga1 = A  + (brow + ar1) * Kd + kt + ak1;
        const u16* gb0 = Bt + (bcol + ar0) * Kd + kt + ak0;
        const u16* gb1 = Bt + (bcol + ar1) * Kd + kt + ak1;
        __builtin_amdgcn_global_load_lds((const __attribute__((address_space(1))) void*)ga0,
            (__attribute__((address_space(3))) void*)(As + c0 * 8), 16, 0, 0);
        __builtin_amdgcn_global_load_lds((const __attribute__((address_space(1))) void*)ga1,
            (__attribute__((address_space(3))) void*)(As + c1 * 8), 16, 0, 0);
        __builtin_amdgcn_global_load_lds((const __attribute__((address_space(1))) void*)gb0,
            (__attribute__((address_space(3))) void*)(Bs + c0 * 8), 16, 0, 0);
        __builtin_amdgcn_global_load_lds((const __attribute__((address_space(1))) void*)gb1,
            (__attribute__((address_space(3))) void*)(Bs + c1 * 8), 16, 0, 0);
        __syncthreads();

        bf16x8 a[4], b[4];
        #pragma unroll
        for (int m = 0; m < 4; ++m)
            a[m] = *(const bf16x8*)(As + (wr * 64 + m * 16 + lrow) * 32 + lk);
        #pragma unroll
        for (int n = 0; n < 4; ++n)
            b[n] = *(const bf16x8*)(Bs + (wc * 64 + n * 16 + lrow) * 32 + lk);
        #pragma unroll
        for (int m = 0; m < 4; ++m)
            #pragma unroll
            for (int n = 0; n < 4; ++n)
                acc[m][n] = __builtin_amdgcn_mfma_f32_16x16x32_bf16(a[m], b[n], acc[m][n], 0, 0, 0);
        __syncthreads();
    }

    const int orow = (l >> 4) * 4, ocol = l & 15;
    #pragma unroll
    for (int m = 0; m < 4; ++m) {
        const size_t rb = brow + wr * 64 + m * 16 + orow;
        #pragma unroll
        for (int n = 0; n < 4; ++n) {
            const size_t cb = bcol + wc * 64 + n * 16 + ocol;
            #pragma unroll
            for (int rr = 0; rr < 4; ++rr)
                C[(rb + rr) * (size_t)N + cb] = acc[m][n][rr];
        }
    }
}

// ---------------- block reduce helpers ----------------
__device__ inline float blockSum(float v, float* red) {
    #pragma unroll
    for (int o = 32; o > 0; o >>= 1) v += __shfl_down(v, o);
    __syncthreads();
    if ((threadIdx.x & 63) == 0) red[threadIdx.x >> 6] = v;
    __syncthreads();
    return red[0] + red[1] + red[2] + red[3];
}
__device__ inline float blockMax(float v, float* red) {
    #pragma unroll
    for (int o = 32; o > 0; o >>= 1) v = fmaxf(v, __shfl_down(v, o));
    __syncthreads();
    if ((threadIdx.x & 63) == 0) red[threadIdx.x >> 6] = v;
    __syncthreads();
    return fmaxf(fmaxf(red[0], red[1]), fmaxf(red[2], red[3]));
}

// ---------------- bias + LayerNorm -> bf16 ----------------
__global__ void ln_k(const float* __restrict__ Hpre, const float* __restrict__ bias,
                     const float* __restrict__ gamma, const float* __restrict__ beta,
                     u16* __restrict__ Hb) {
    __shared__ float red[4];
    const int r = blockIdx.x, t = threadIdx.x;
    float4 x4 = *(const float4*)(Hpre + (size_t)r * HD + t * 4);
    float4 b4 = *(const float4*)(bias + t * 4);
    float x[4] = { x4.x + b4.x, x4.y + b4.y, x4.z + b4.z, x4.w + b4.w };
    float s = x[0] + x[1] + x[2] + x[3];
    float mu = blockSum(s, red) * (1.0f / HD);
    float d0 = x[0] - mu, d1 = x[1] - mu, d2 = x[2] - mu, d3 = x[3] - mu;
    float vs = d0 * d0 + d1 * d1 + d2 * d2 + d3 * d3;
    float var = blockSum(vs, red) * (1.0f / HD);
    float rs = rsqrtf(var + LN_EPS);
    float4 g4 = *(const float4*)(gamma + t * 4);
    float4 e4 = *(const float4*)(beta + t * 4);
    float y0 = d0 * rs * g4.x + e4.x;
    float y1 = d1 * rs * g4.y + e4.y;
    float y2 = d2 * rs * g4.z + e4.z;
    float y3 = d3 * rs * g4.w + e4.w;
    *(uint2*)(Hb + (size_t)r * HD + t * 4) = pack4(y0, y1, y2, y3);
}

// ---------------- row softmax + losses ----------------
__global__ __launch_bounds__(256)
void softmax_loss_k(const float* __restrict__ logits, float* __restrict__ peld,
                    float* __restrict__ pelp, double* __restrict__ acc4) {
    __shared__ float red[4];
    __shared__ float sdiag;
    const int r = blockIdx.x, t = threadIdx.x;
    const float* row = logits + (size_t)r * KSEL;
    float x[32];
    float mx = -3.4e38f;
    #pragma unroll
    for (int i = 0; i < 8; ++i) {
        float4 v = *(const float4*)(row + i * 1024 + t * 4);
        x[i * 4 + 0] = v.x; x[i * 4 + 1] = v.y; x[i * 4 + 2] = v.z; x[i * 4 + 3] = v.w;
        mx = fmaxf(mx, fmaxf(fmaxf(v.x, v.y), fmaxf(v.z, v.w)));
    }
    const float m = blockMax(mx, red);
    float s = 0.f;
    #pragma unroll
    for (int i = 0; i < 32; ++i) s += expf(x[i] - m);
    const float Z = blockSum(s, red);
    const float lz = logf(Z);
    const float invZ = 1.0f / Z;
    float pe = 0.f;
    #pragma unroll
    for (int i = 0; i < 8; ++i) {
        #pragma unroll
        for (int j = 0; j < 4; ++j) {
            const int c = i * 1024 + t * 4 + j;
            const float xv = x[i * 4 + j];
            const float p = expf(xv - m) * invZ;
            pe += fabsf(p - ((c == r) ? 1.0f : 0.0f) + PD_EPS);
            if (c == r) sdiag = xv;
        }
    }
    const float PE = blockSum(pe, red);
    if (t == 0) {
        const float pl = m + lz - sdiag;
        peld[r] = PE;
        pelp[r] = pl;
        atomicAdd(acc4 + 0, (double)PE);
        atomicAdd(acc4 + 1, (double)PE * (double)PE);
        atomicAdd(acc4 + 2, (double)pl);
        atomicAdd(acc4 + 3, (double)pl * (double)pl);
    }
}

__global__ void finalize_k(const double* __restrict__ acc4, float* __restrict__ out) {
    const double s1 = acc4[0], s2 = acc4[1], s3 = acc4[2], s4 = acc4[3];
    const double Kd = (double)KSEL;
    const double denom = Kd + 1e-5;
    float* o = out + (size_t)KSEL * KSEL + 2 * KSEL;
    o[0] = (float)(s1 / denom);
    o[1] = (float)(s3 / denom);
    o[2] = (float)((s2 - s1 * s1 / Kd) / (Kd - 1.0));
    o[3] = (float)((s4 - s3 * s3 / Kd) / (Kd - 1.0));
}

extern "C" void kernel_launch(void* const* d_in, const int* in_sizes, int n_in,
                              void* d_out, int out_size, void* d_ws, size_t ws_size,
                              hipStream_t stream) {
    const float* msp   = (const float*)d_in[0];
    const float* lab   = (const float*)d_in[1];
    const void*  mask  = d_in[2];
    const float* W     = (const float*)d_in[3];
    const float* bias  = (const float*)d_in[4];
    const float* gamma = (const float*)d_in[5];
    const float* beta  = (const float*)d_in[6];
    float* out = (float*)d_out;
    char*  ws  = (char*)d_ws;

    int*    idx     = (int*)ws;                         // 32 KB
    double* acc4    = (double*)(ws + 32768);            // 32 B
    u16*    wBf     = (u16*)(ws + 65536);               // 2 MB
    u16*    labelsB = (u16*)(ws + (size_t)(4  << 20));  // 16 MB
    u16*    hB      = (u16*)(ws + (size_t)(20 << 20));  // 16 MB
    u16*    predsB  = (u16*)d_out;                      // 16 MB scratch (dead before GEMM2)
    float*  hPre    = out + ((size_t)8 << 20);          // 32 MB scratch (dead before GEMM2)

    hipMemsetAsync(acc4, 0, 4 * sizeof(double), stream);
    compact_mask_k<<<1, 1024, 0, stream>>>((const uint8_t*)mask, (const int32_t*)mask, idx);
    convert_w_k<<<(HD * HD) / 1024, 256, 0, stream>>>(W, wBf);
    gather_k<<<KSEL, 256, 0, stream>>>(msp, lab, idx, predsB, labelsB);
    gemm_nt_bf16<<<(KSEL / 128) * (HD / 128), 256, 0, stream>>>(predsB, wBf, hPre, KSEL, HD, HD);
    ln_k<<<KSEL, 256, 0, stream>>>(hPre, bias, gamma, beta, hB);
    gemm_nt_bf16<<<(KSEL / 128) * (KSEL / 128), 256, 0, stream>>>(hB, labelsB, out, KSEL, KSEL, HD);
    softmax_loss_k<<<KSEL, 256, 0, stream>>>(out, out + (size_t)KSEL * KSEL,
                                             out + (size_t)KSEL * KSEL + KSEL, acc4);
    finalize_k<<<1, 1, 0, stream>>>(acc4, out);
}

// Round 2
// 361.745 us; speedup vs baseline: 1.9826x; 1.9826x over previous
//
#include <hip/hip_runtime.h>
#include <cstdint>

#define NROWS 32768
#define HD    1024
#define KSEL  8192
#define LN_EPS 1e-12f
#define PD_EPS 1e-6f

typedef unsigned short u16;
typedef __bf16 bf16x8 __attribute__((ext_vector_type(8)));
typedef float  f32x4  __attribute__((ext_vector_type(4)));

__device__ inline u16 f2bf(float f) {
    union { float f; uint32_t u; } x; x.f = f;
    uint32_t r = (x.u + 0x7fffu + ((x.u >> 16) & 1u)) >> 16;
    return (u16)r;
}

__device__ inline uint2 pack4(float a, float b, float c, float d) {
    uint2 r;
    r.x = (uint32_t)f2bf(a) | ((uint32_t)f2bf(b) << 16);
    r.y = (uint32_t)f2bf(c) | ((uint32_t)f2bf(d) << 16);
    return r;
}

// ---------------- mask compaction (layout-robust) ----------------
__global__ void compact_mask_k(const uint8_t* mb, const int32_t* mi, int* idx) {
    __shared__ int cnt[1024];
    __shared__ int tmp[1024];
    __shared__ int mode_s;
    const int t = threadIdx.x;
    const int per = NROWS / 1024;      // 32
    const int base = t * per;
    int c0 = 0;
    for (int i = 0; i < per; ++i) c0 += (mb[base + i] != 0);
    tmp[t] = c0;
    __syncthreads();
    for (int off = 512; off > 0; off >>= 1) {
        if (t < off) tmp[t] += tmp[t + off];
        __syncthreads();
    }
    if (t == 0) mode_s = (tmp[0] == KSEL) ? 0 : 1;
    __syncthreads();
    const int mode = mode_s;
    int c = c0;
    if (mode) { c = 0; for (int i = 0; i < per; ++i) c += (mi[base + i] != 0); }
    cnt[t] = c;
    __syncthreads();
    // inclusive scan
    for (int off = 1; off < 1024; off <<= 1) {
        int add = (t >= off) ? cnt[t - off] : 0;
        __syncthreads();
        cnt[t] += add;
        __syncthreads();
    }
    int pos = cnt[t] - c;
    for (int i = 0; i < per; ++i) {
        bool v = mode ? (mi[base + i] != 0) : (mb[base + i] != 0);
        if (v) idx[pos++] = base + i;
    }
}

// ---------------- dense_w -> bf16 ----------------
__global__ void convert_w_k(const float* __restrict__ W, u16* __restrict__ Wb) {
    int i = (blockIdx.x * 256 + threadIdx.x) * 4;
    float4 v = *(const float4*)(W + i);
    *(uint2*)(Wb + i) = pack4(v.x, v.y, v.z, v.w);
}

// ---------------- gather selected rows -> bf16 ----------------
__global__ void gather_k(const float* __restrict__ msp, const float* __restrict__ lab,
                         const int* __restrict__ idx,
                         u16* __restrict__ predsB, u16* __restrict__ labelsB) {
    const int r = blockIdx.x;
    const int src = idx[r];
    const int t = threadIdx.x;
    float4 p = *(const float4*)(msp + (size_t)src * HD + t * 4);
    float4 q = *(const float4*)(lab + (size_t)src * HD + t * 4);
    *(uint2*)(predsB  + (size_t)r * HD + t * 4) = pack4(p.x, p.y, p.z, p.w);
    *(uint2*)(labelsB + (size_t)r * HD + t * 4) = pack4(q.x, q.y, q.z, q.w);
}

// ---------------- bf16 NT GEMM: C[M,N] = A[M,Kd] * Bt[N,Kd]^T ----------------
__global__ __launch_bounds__(256)
void gemm_nt_bf16(const u16* __restrict__ A, const u16* __restrict__ Bt,
                  float* __restrict__ C, int M, int N, int Kd) {
    __shared__ u16 As[128 * 32];
    __shared__ u16 Bs[128 * 32];
    const int nx  = N >> 7;
    const int nwg = (M >> 7) * nx;
    int bid = blockIdx.x;
    int wg  = ((nwg & 7) == 0) ? ((bid & 7) * (nwg >> 3) + (bid >> 3)) : bid;
    const int bm = wg / nx, bn = wg % nx;

    const int tid = threadIdx.x;
    const int l = tid & 63;
    const int w = tid >> 6;
    const int wr = w >> 1, wc = w & 1;
    const size_t brow = (size_t)bm * 128, bcol = (size_t)bn * 128;

    f32x4 acc[4][4] = {};

    const int lrow = l & 15, lk = (l >> 4) * 8;
    const int c0 = tid, c1 = tid + 256;
    const int ar0 = c0 >> 2, ak0 = (c0 & 3) * 8;
    const int ar1 = c1 >> 2, ak1 = (c1 & 3) * 8;

    for (int kt = 0; kt < Kd; kt += 32) {
        const u16* ga0 = A  + (brow + ar0) * Kd + kt + ak0;
        const u16* ga1 = A  + (brow + ar1) * Kd + kt + ak1;
        const u16* gb0 = Bt + (bcol + ar0) * Kd + kt + ak0;
        const u16* gb1 = Bt + (bcol + ar1) * Kd + kt + ak1;
        __builtin_amdgcn_global_load_lds((const __attribute__((address_space(1))) void*)ga0,
            (__attribute__((address_space(3))) void*)(As + c0 * 8), 16, 0, 0);
        __builtin_amdgcn_global_load_lds((const __attribute__((address_space(1))) void*)ga1,
            (__attribute__((address_space(3))) void*)(As + c1 * 8), 16, 0, 0);
        __builtin_amdgcn_global_load_lds((const __attribute__((address_space(1))) void*)gb0,
            (__attribute__((address_space(3))) void*)(Bs + c0 * 8), 16, 0, 0);
        __builtin_amdgcn_global_load_lds((const __attribute__((address_space(1))) void*)gb1,
            (__attribute__((address_space(3))) void*)(Bs + c1 * 8), 16, 0, 0);
        __syncthreads();

        bf16x8 a[4], b[4];
        #pragma unroll
        for (int m = 0; m < 4; ++m)
            a[m] = *(const bf16x8*)(As + (wr * 64 + m * 16 + lrow) * 32 + lk);
        #pragma unroll
        for (int n = 0; n < 4; ++n)
            b[n] = *(const bf16x8*)(Bs + (wc * 64 + n * 16 + lrow) * 32 + lk);
        #pragma unroll
        for (int m = 0; m < 4; ++m)
            #pragma unroll
            for (int n = 0; n < 4; ++n)
                acc[m][n] = __builtin_amdgcn_mfma_f32_16x16x32_bf16(a[m], b[n], acc[m][n], 0, 0, 0);
        __syncthreads();
    }

    const int orow = (l >> 4) * 4, ocol = l & 15;
    #pragma unroll
    for (int m = 0; m < 4; ++m) {
        const size_t rb = brow + wr * 64 + m * 16 + orow;
        #pragma unroll
        for (int n = 0; n < 4; ++n) {
            const size_t cb = bcol + wc * 64 + n * 16 + ocol;
            #pragma unroll
            for (int rr = 0; rr < 4; ++rr)
                C[(rb + rr) * (size_t)N + cb] = acc[m][n][rr];
        }
    }
}

// ---------------- block reduce helpers ----------------
__device__ inline float blockSum(float v, float* red) {
    #pragma unroll
    for (int o = 32; o > 0; o >>= 1) v += __shfl_down(v, o);
    __syncthreads();
    if ((threadIdx.x & 63) == 0) red[threadIdx.x >> 6] = v;
    __syncthreads();
    return red[0] + red[1] + red[2] + red[3];
}
__device__ inline float blockMax(float v, float* red) {
    #pragma unroll
    for (int o = 32; o > 0; o >>= 1) v = fmaxf(v, __shfl_down(v, o));
    __syncthreads();
    if ((threadIdx.x & 63) == 0) red[threadIdx.x >> 6] = v;
    __syncthreads();
    return fmaxf(fmaxf(red[0], red[1]), fmaxf(red[2], red[3]));
}

// ---------------- bias + LayerNorm -> bf16 ----------------
__global__ void ln_k(const float* __restrict__ Hpre, const float* __restrict__ bias,
                     const float* __restrict__ gamma, const float* __restrict__ beta,
                     u16* __restrict__ Hb) {
    __shared__ float red[4];
    const int r = blockIdx.x, t = threadIdx.x;
    float4 x4 = *(const float4*)(Hpre + (size_t)r * HD + t * 4);
    float4 b4 = *(const float4*)(bias + t * 4);
    float x[4] = { x4.x + b4.x, x4.y + b4.y, x4.z + b4.z, x4.w + b4.w };
    float s = x[0] + x[1] + x[2] + x[3];
    float mu = blockSum(s, red) * (1.0f / HD);
    float d0 = x[0] - mu, d1 = x[1] - mu, d2 = x[2] - mu, d3 = x[3] - mu;
    float vs = d0 * d0 + d1 * d1 + d2 * d2 + d3 * d3;
    float var = blockSum(vs, red) * (1.0f / HD);
    float rs = rsqrtf(var + LN_EPS);
    float4 g4 = *(const float4*)(gamma + t * 4);
    float4 e4 = *(const float4*)(beta + t * 4);
    float y0 = d0 * rs * g4.x + e4.x;
    float y1 = d1 * rs * g4.y + e4.y;
    float y2 = d2 * rs * g4.z + e4.z;
    float y3 = d3 * rs * g4.w + e4.w;
    *(uint2*)(Hb + (size_t)r * HD + t * 4) = pack4(y0, y1, y2, y3);
}

// ---------------- row softmax + losses (no atomics) ----------------
__global__ __launch_bounds__(256)
void softmax_loss_k(const float* __restrict__ logits, float* __restrict__ peld,
                    float* __restrict__ pelp) {
    __shared__ float red[4];
    __shared__ float sdiag;
    const int r = blockIdx.x, t = threadIdx.x;
    const float* row = logits + (size_t)r * KSEL;
    float x[32];
    float mx = -3.4e38f;
    #pragma unroll
    for (int i = 0; i < 8; ++i) {
        float4 v = *(const float4*)(row + i * 1024 + t * 4);
        const int c = i * 1024 + t * 4;
        if (c == r) sdiag = v.x;
        else if (c + 1 == r) sdiag = v.y;
        else if (c + 2 == r) sdiag = v.z;
        else if (c + 3 == r) sdiag = v.w;
        x[i * 4 + 0] = v.x; x[i * 4 + 1] = v.y; x[i * 4 + 2] = v.z; x[i * 4 + 3] = v.w;
        mx = fmaxf(mx, fmaxf(fmaxf(v.x, v.y), fmaxf(v.z, v.w)));
    }
    const float m = blockMax(mx, red);
    float s = 0.f;
    #pragma unroll
    for (int i = 0; i < 32; ++i) {
        const float e = expf(x[i] - m);
        x[i] = e;                 // reuse: store exp, drop raw logit
        s += e;
    }
    const float Z = blockSum(s, red);
    const float invZ = 1.0f / Z;
    float pe = 0.f;
    #pragma unroll
    for (int i = 0; i < 8; ++i) {
        #pragma unroll
        for (int j = 0; j < 4; ++j) {
            const int c = i * 1024 + t * 4 + j;
            const float p = x[i * 4 + j] * invZ;
            pe += fabsf(p - ((c == r) ? 1.0f : 0.0f) + PD_EPS);
        }
    }
    const float PE = blockSum(pe, red);
    if (t == 0) {
        peld[r] = PE;
        pelp[r] = m + logf(Z) - sdiag;
    }
}

// ---------------- deterministic two-stage f64 reduction ----------------
__global__ __launch_bounds__(1024)
void reduce_k(const float* __restrict__ peld, const float* __restrict__ pelp,
              float* __restrict__ scalars) {
    __shared__ double red[4][16];
    const int t = threadIdx.x;
    double a = 0.0, b = 0.0, c = 0.0, d = 0.0;
    for (int i = t; i < KSEL; i += 1024) {
        const double pd = (double)peld[i];
        const double pp = (double)pelp[i];
        a += pd; b += pd * pd; c += pp; d += pp * pp;
    }
    #pragma unroll
    for (int o = 32; o > 0; o >>= 1) {
        a += __shfl_down(a, o); b += __shfl_down(b, o);
        c += __shfl_down(c, o); d += __shfl_down(d, o);
    }
    const int wv = t >> 6;
    if ((t & 63) == 0) { red[0][wv] = a; red[1][wv] = b; red[2][wv] = c; red[3][wv] = d; }
    __syncthreads();
    if (t == 0) {
        double s1 = 0, s2 = 0, s3 = 0, s4 = 0;
        #pragma unroll
        for (int i = 0; i < 16; ++i) { s1 += red[0][i]; s2 += red[1][i]; s3 += red[2][i]; s4 += red[3][i]; }
        const double Kd = (double)KSEL;
        const double denom = Kd + 1e-5;
        scalars[0] = (float)(s1 / denom);
        scalars[1] = (float)(s3 / denom);
        scalars[2] = (float)((s2 - s1 * s1 / Kd) / (Kd - 1.0));
        scalars[3] = (float)((s4 - s3 * s3 / Kd) / (Kd - 1.0));
    }
}

extern "C" void kernel_launch(void* const* d_in, const int* in_sizes, int n_in,
                              void* d_out, int out_size, void* d_ws, size_t ws_size,
                              hipStream_t stream) {
    const float* msp   = (const float*)d_in[0];
    const float* lab   = (const float*)d_in[1];
    const void*  mask  = d_in[2];
    const float* W     = (const float*)d_in[3];
    const float* bias  = (const float*)d_in[4];
    const float* gamma = (const float*)d_in[5];
    const float* beta  = (const float*)d_in[6];
    float* out = (float*)d_out;
    char*  ws  = (char*)d_ws;

    int*    idx     = (int*)ws;                         // 32 KB
    u16*    wBf     = (u16*)(ws + 65536);               // 2 MB
    u16*    labelsB = (u16*)(ws + (size_t)(4  << 20));  // 16 MB
    u16*    hB      = (u16*)(ws + (size_t)(20 << 20));  // 16 MB
    u16*    predsB  = (u16*)d_out;                      // 16 MB scratch (dead before GEMM2)
    float*  hPre    = out + ((size_t)8 << 20);          // 32 MB scratch (dead before GEMM2)

    float* peld    = out + (size_t)KSEL * KSEL;
    float* pelp    = peld + KSEL;
    float* scalars = pelp + KSEL;

    compact_mask_k<<<1, 1024, 0, stream>>>((const uint8_t*)mask, (const int32_t*)mask, idx);
    convert_w_k<<<(HD * HD) / 1024, 256, 0, stream>>>(W, wBf);
    gather_k<<<KSEL, 256, 0, stream>>>(msp, lab, idx, predsB, labelsB);
    gemm_nt_bf16<<<(KSEL / 128) * (HD / 128), 256, 0, stream>>>(predsB, wBf, hPre, KSEL, HD, HD);
    ln_k<<<KSEL, 256, 0, stream>>>(hPre, bias, gamma, beta, hB);
    gemm_nt_bf16<<<(KSEL / 128) * (KSEL / 128), 256, 0, stream>>>(hB, labelsB, out, KSEL, KSEL, HD);
    softmax_loss_k<<<KSEL, 256, 0, stream>>>(out, peld, pelp);
    reduce_k<<<1, 1024, 0, stream>>>(peld, pelp, scalars);
}

// Round 3
// 308.525 us; speedup vs baseline: 2.3246x; 1.1725x over previous
//
#include <hip/hip_runtime.h>
#include <cstdint>

#define NROWS 32768
#define HD    1024
#define KSEL  8192
#define LN_EPS 1e-12f
#define PD_EPS 1e-6f

typedef unsigned short u16;
typedef __bf16 bf16x8 __attribute__((ext_vector_type(8)));
typedef float  f32x4  __attribute__((ext_vector_type(4)));

__device__ inline u16 f2bf(float f) {
    union { float f; uint32_t u; } x; x.f = f;
    uint32_t r = (x.u + 0x7fffu + ((x.u >> 16) & 1u)) >> 16;
    return (u16)r;
}

__device__ inline uint2 pack4(float a, float b, float c, float d) {
    uint2 r;
    r.x = (uint32_t)f2bf(a) | ((uint32_t)f2bf(b) << 16);
    r.y = (uint32_t)f2bf(c) | ((uint32_t)f2bf(d) << 16);
    return r;
}

// ---------------- mask compaction (layout-robust) ----------------
__global__ void compact_mask_k(const uint8_t* mb, const int32_t* mi, int* idx) {
    __shared__ int cnt[1024];
    __shared__ int tmp[1024];
    __shared__ int mode_s;
    const int t = threadIdx.x;
    const int per = NROWS / 1024;      // 32
    const int base = t * per;
    int c0 = 0;
    for (int i = 0; i < per; ++i) c0 += (mb[base + i] != 0);
    tmp[t] = c0;
    __syncthreads();
    for (int off = 512; off > 0; off >>= 1) {
        if (t < off) tmp[t] += tmp[t + off];
        __syncthreads();
    }
    if (t == 0) mode_s = (tmp[0] == KSEL) ? 0 : 1;
    __syncthreads();
    const int mode = mode_s;
    int c = c0;
    if (mode) { c = 0; for (int i = 0; i < per; ++i) c += (mi[base + i] != 0); }
    cnt[t] = c;
    __syncthreads();
    for (int off = 1; off < 1024; off <<= 1) {
        int add = (t >= off) ? cnt[t - off] : 0;
        __syncthreads();
        cnt[t] += add;
        __syncthreads();
    }
    int pos = cnt[t] - c;
    for (int i = 0; i < per; ++i) {
        bool v = mode ? (mi[base + i] != 0) : (mb[base + i] != 0);
        if (v) idx[pos++] = base + i;
    }
}

// ---------------- dense_w -> bf16 ----------------
__global__ void convert_w_k(const float* __restrict__ W, u16* __restrict__ Wb) {
    int i = (blockIdx.x * 256 + threadIdx.x) * 4;
    float4 v = *(const float4*)(W + i);
    *(uint2*)(Wb + i) = pack4(v.x, v.y, v.z, v.w);
}

// ---------------- gather selected rows -> bf16 ----------------
__global__ void gather_k(const float* __restrict__ msp, const float* __restrict__ lab,
                         const int* __restrict__ idx,
                         u16* __restrict__ predsB, u16* __restrict__ labelsB) {
    const int r = blockIdx.x;
    const int src = idx[r];
    const int t = threadIdx.x;
    float4 p = *(const float4*)(msp + (size_t)src * HD + t * 4);
    float4 q = *(const float4*)(lab + (size_t)src * HD + t * 4);
    *(uint2*)(predsB  + (size_t)r * HD + t * 4) = pack4(p.x, p.y, p.z, p.w);
    *(uint2*)(labelsB + (size_t)r * HD + t * 4) = pack4(q.x, q.y, q.z, q.w);
}

// =======================================================================
// 256x256 tile, BK=64, 8 waves (2M x 4N), pipelined with counted vmcnt.
// LDS 160KB: A triple-buffered (3 x 32KB), B double-buffered (2 x 32KB).
// Swizzle: 16B-slot ^= (row&7); written via pre-swizzled GLOBAL source
// (global_load_lds writes LDS linearly), read with swizzled ds_read.
// Schedule per K-tile t (4 phases):
//   P1: ds_read A(kk0) x8 + B n0,n1(kk0); stage B(t+1) L0,L1 -> barrier,
//       lgkmcnt(0), setprio1, 16 MFMA, setprio0, barrier
//   P2: ds_read B n2,n3(kk0); stage B(t+1) L2,L3; 16 MFMA
//   P3: ds_read A(kk1) x8 + B n0,n1(kk1); stage A(t+2) L0,L1; 16 MFMA
//   P4: ds_read B n2,n3(kk1); stage A(t+2) L2,L3; 16 MFMA;
//       vmcnt(4) [all but A(t+2) retired], barrier
// Proof sketch: stages only target buffers whose last reader finished
// before the previous iteration-end barrier; vmcnt(4) at iter end retires
// A(t+1) and B(t+1) before iteration t+1 reads them.
// =======================================================================
#define STAGE(XPTR, ROWBASE, KT, I, LBASE) do {                                      \
    const int f_ = (I) * 512 + tid;                                                  \
    const int r_ = f_ >> 3;                                                          \
    const int sp_ = (f_ & 7) ^ (r_ & 7);                                             \
    const u16* g_ = (XPTR) + (size_t)((ROWBASE) + r_) * Kd + (KT) * 64 + sp_ * 8;    \
    __builtin_amdgcn_global_load_lds(                                                \
        (const __attribute__((address_space(1))) void*)g_,                           \
        (__attribute__((address_space(3))) void*)(lds + (LBASE) + f_ * 8), 16, 0, 0);\
} while (0)

#define LGKM0() do {                                                \
    asm volatile("s_waitcnt lgkmcnt(0)" ::: "memory");              \
    __builtin_amdgcn_sched_barrier(0);                              \
} while (0)

__global__ __launch_bounds__(512, 2)
void gemm256_k(const u16* __restrict__ A, const u16* __restrict__ Bt,
               float* __restrict__ C, int M, int N, int Kd) {
    extern __shared__ u16 lds[];
    const int nx  = N >> 8;
    const int nwg = (M >> 8) * nx;
    int bid = blockIdx.x;
    int wg  = ((nwg & 7) == 0) ? ((bid & 7) * (nwg >> 3) + (bid >> 3)) : bid;
    const int bm = wg / nx, bn = wg % nx;
    const size_t brow = (size_t)bm << 8, bcol = (size_t)bn << 8;
    const int tid = threadIdx.x;
    const int l = tid & 63, wid = tid >> 6;
    const int wm = wid >> 2, wn = wid & 3;     // 2 x 4 waves
    const int lr = l & 15, lq = l >> 4;
    const int sw = lr & 7;                     // read-side swizzle (row&7 == lr&7)

    f32x4 acc[8][4] = {};

    // element offsets of the 16B fragment slots (loop-invariant except buffer base)
    // A-frag m, kk: aB + (wm*128 + m*16 + lr)*64 + ((kk*4+lq)^sw)*8
    const int arow = (wm * 128 + lr) * 64;
    const int brow2 = (wn * 64 + lr) * 64;
    const int s0 = (lq ^ sw) * 8;              // kk0 slot byte-group
    const int s1 = ((4 + lq) ^ sw) * 8;        // kk1

    // ---- prologue: stage A(0), B(0), A(1); wait for A(0),B(0) ----
    #pragma unroll
    for (int i = 0; i < 4; ++i) STAGE(A,  brow, 0, i, 0);
    #pragma unroll
    for (int i = 0; i < 4; ++i) STAGE(Bt, bcol, 0, i, 49152);
    #pragma unroll
    for (int i = 0; i < 4; ++i) STAGE(A,  brow, 1, i, 16384);
    asm volatile("s_waitcnt vmcnt(4)" ::: "memory");
    __builtin_amdgcn_s_barrier();

    const int T = Kd >> 6;
    int abi = 0;                                // t % 3
    #pragma unroll 1
    for (int t = 0; t < T; ++t) {
        const int aB = abi * 16384;
        const int bB = 49152 + (t & 1) * 16384;
        const int aN = (abi >= 1 ? abi - 1 : 2) * 16384;   // (t+2)%3
        const int bN = 49152 + ((t + 1) & 1) * 16384;
        bf16x8 a[8], b0, b1, b2, b3;

        // ---- P1: A kk0, B n0/n1 kk0; stage B(t+1) L0,L1 ----
        #pragma unroll
        for (int m = 0; m < 8; ++m)
            a[m] = *(const bf16x8*)(lds + aB + arow + m * 1024 + s0);
        b0 = *(const bf16x8*)(lds + bB + brow2 + 0 * 1024 + s0);
        b1 = *(const bf16x8*)(lds + bB + brow2 + 1 * 1024 + s0);
        if (t + 1 < T) { STAGE(Bt, bcol, t + 1, 0, bN); STAGE(Bt, bcol, t + 1, 1, bN); }
        __builtin_amdgcn_s_barrier();
        LGKM0();
        __builtin_amdgcn_s_setprio(1);
        #pragma unroll
        for (int m = 0; m < 8; ++m)
            acc[m][0] = __builtin_amdgcn_mfma_f32_16x16x32_bf16(a[m], b0, acc[m][0], 0, 0, 0);
        #pragma unroll
        for (int m = 0; m < 8; ++m)
            acc[m][1] = __builtin_amdgcn_mfma_f32_16x16x32_bf16(a[m], b1, acc[m][1], 0, 0, 0);
        __builtin_amdgcn_s_setprio(0);
        __builtin_amdgcn_s_barrier();

        // ---- P2: B n2/n3 kk0; stage B(t+1) L2,L3 ----
        b2 = *(const bf16x8*)(lds + bB + brow2 + 2 * 1024 + s0);
        b3 = *(const bf16x8*)(lds + bB + brow2 + 3 * 1024 + s0);
        if (t + 1 < T) { STAGE(Bt, bcol, t + 1, 2, bN); STAGE(Bt, bcol, t + 1, 3, bN); }
        __builtin_amdgcn_s_barrier();
        LGKM0();
        __builtin_amdgcn_s_setprio(1);
        #pragma unroll
        for (int m = 0; m < 8; ++m)
            acc[m][2] = __builtin_amdgcn_mfma_f32_16x16x32_bf16(a[m], b2, acc[m][2], 0, 0, 0);
        #pragma unroll
        for (int m = 0; m < 8; ++m)
            acc[m][3] = __builtin_amdgcn_mfma_f32_16x16x32_bf16(a[m], b3, acc[m][3], 0, 0, 0);
        __builtin_amdgcn_s_setprio(0);
        __builtin_amdgcn_s_barrier();

        // ---- P3: A kk1, B n0/n1 kk1; stage A(t+2) L0,L1 ----
        #pragma unroll
        for (int m = 0; m < 8; ++m)
            a[m] = *(const bf16x8*)(lds + aB + arow + m * 1024 + s1);
        b0 = *(const bf16x8*)(lds + bB + brow2 + 0 * 1024 + s1);
        b1 = *(const bf16x8*)(lds + bB + brow2 + 1 * 1024 + s1);
        if (t + 2 < T) { STAGE(A, brow, t + 2, 0, aN); STAGE(A, brow, t + 2, 1, aN); }
        __builtin_amdgcn_s_barrier();
        LGKM0();
        __builtin_amdgcn_s_setprio(1);
        #pragma unroll
        for (int m = 0; m < 8; ++m)
            acc[m][0] = __builtin_amdgcn_mfma_f32_16x16x32_bf16(a[m], b0, acc[m][0], 0, 0, 0);
        #pragma unroll
        for (int m = 0; m < 8; ++m)
            acc[m][1] = __builtin_amdgcn_mfma_f32_16x16x32_bf16(a[m], b1, acc[m][1], 0, 0, 0);
        __builtin_amdgcn_s_setprio(0);
        __builtin_amdgcn_s_barrier();

        // ---- P4: B n2/n3 kk1; stage A(t+2) L2,L3; iteration-end vmcnt ----
        b2 = *(const bf16x8*)(lds + bB + brow2 + 2 * 1024 + s1);
        b3 = *(const bf16x8*)(lds + bB + brow2 + 3 * 1024 + s1);
        if (t + 2 < T) { STAGE(A, brow, t + 2, 2, aN); STAGE(A, brow, t + 2, 3, aN); }
        __builtin_amdgcn_s_barrier();
        LGKM0();
        __builtin_amdgcn_s_setprio(1);
        #pragma unroll
        for (int m = 0; m < 8; ++m)
            acc[m][2] = __builtin_amdgcn_mfma_f32_16x16x32_bf16(a[m], b2, acc[m][2], 0, 0, 0);
        #pragma unroll
        for (int m = 0; m < 8; ++m)
            acc[m][3] = __builtin_amdgcn_mfma_f32_16x16x32_bf16(a[m], b3, acc[m][3], 0, 0, 0);
        __builtin_amdgcn_s_setprio(0);
        if (t < T - 2) { asm volatile("s_waitcnt vmcnt(4)" ::: "memory"); }
        else           { asm volatile("s_waitcnt vmcnt(0)" ::: "memory"); }
        __builtin_amdgcn_s_barrier();

        abi = (abi == 2) ? 0 : abi + 1;
    }

    // ---- epilogue: C write ----
    #pragma unroll
    for (int m = 0; m < 8; ++m) {
        const size_t rb = brow + wm * 128 + m * 16 + lq * 4;
        #pragma unroll
        for (int n = 0; n < 4; ++n) {
            const size_t cb = bcol + wn * 64 + n * 16 + lr;
            #pragma unroll
            for (int rr = 0; rr < 4; ++rr)
                C[(rb + rr) * (size_t)N + cb] = acc[m][n][rr];
        }
    }
}

// ---------------- block reduce helpers ----------------
__device__ inline float blockSum(float v, float* red) {
    #pragma unroll
    for (int o = 32; o > 0; o >>= 1) v += __shfl_down(v, o);
    __syncthreads();
    if ((threadIdx.x & 63) == 0) red[threadIdx.x >> 6] = v;
    __syncthreads();
    return red[0] + red[1] + red[2] + red[3];
}
__device__ inline float blockMax(float v, float* red) {
    #pragma unroll
    for (int o = 32; o > 0; o >>= 1) v = fmaxf(v, __shfl_down(v, o));
    __syncthreads();
    if ((threadIdx.x & 63) == 0) red[threadIdx.x >> 6] = v;
    __syncthreads();
    return fmaxf(fmaxf(red[0], red[1]), fmaxf(red[2], red[3]));
}

// ---------------- bias + LayerNorm -> bf16 ----------------
__global__ void ln_k(const float* __restrict__ Hpre, const float* __restrict__ bias,
                     const float* __restrict__ gamma, const float* __restrict__ beta,
                     u16* __restrict__ Hb) {
    __shared__ float red[4];
    const int r = blockIdx.x, t = threadIdx.x;
    float4 x4 = *(const float4*)(Hpre + (size_t)r * HD + t * 4);
    float4 b4 = *(const float4*)(bias + t * 4);
    float x[4] = { x4.x + b4.x, x4.y + b4.y, x4.z + b4.z, x4.w + b4.w };
    float s = x[0] + x[1] + x[2] + x[3];
    float mu = blockSum(s, red) * (1.0f / HD);
    float d0 = x[0] - mu, d1 = x[1] - mu, d2 = x[2] - mu, d3 = x[3] - mu;
    float vs = d0 * d0 + d1 * d1 + d2 * d2 + d3 * d3;
    float var = blockSum(vs, red) * (1.0f / HD);
    float rs = rsqrtf(var + LN_EPS);
    float4 g4 = *(const float4*)(gamma + t * 4);
    float4 e4 = *(const float4*)(beta + t * 4);
    float y0 = d0 * rs * g4.x + e4.x;
    float y1 = d1 * rs * g4.y + e4.y;
    float y2 = d2 * rs * g4.z + e4.z;
    float y3 = d3 * rs * g4.w + e4.w;
    *(uint2*)(Hb + (size_t)r * HD + t * 4) = pack4(y0, y1, y2, y3);
}

// ---------------- row softmax + losses (no atomics) ----------------
__global__ __launch_bounds__(256)
void softmax_loss_k(const float* __restrict__ logits, float* __restrict__ peld,
                    float* __restrict__ pelp) {
    __shared__ float red[4];
    __shared__ float sdiag;
    const int r = blockIdx.x, t = threadIdx.x;
    const float* row = logits + (size_t)r * KSEL;
    float x[32];
    float mx = -3.4e38f;
    #pragma unroll
    for (int i = 0; i < 8; ++i) {
        float4 v = *(const float4*)(row + i * 1024 + t * 4);
        const int c = i * 1024 + t * 4;
        if (c == r) sdiag = v.x;
        else if (c + 1 == r) sdiag = v.y;
        else if (c + 2 == r) sdiag = v.z;
        else if (c + 3 == r) sdiag = v.w;
        x[i * 4 + 0] = v.x; x[i * 4 + 1] = v.y; x[i * 4 + 2] = v.z; x[i * 4 + 3] = v.w;
        mx = fmaxf(mx, fmaxf(fmaxf(v.x, v.y), fmaxf(v.z, v.w)));
    }
    const float m = blockMax(mx, red);
    float s = 0.f;
    #pragma unroll
    for (int i = 0; i < 32; ++i) {
        const float e = expf(x[i] - m);
        x[i] = e;
        s += e;
    }
    const float Z = blockSum(s, red);
    const float invZ = 1.0f / Z;
    float pe = 0.f;
    #pragma unroll
    for (int i = 0; i < 8; ++i) {
        #pragma unroll
        for (int j = 0; j < 4; ++j) {
            const int c = i * 1024 + t * 4 + j;
            const float p = x[i * 4 + j] * invZ;
            pe += fabsf(p - ((c == r) ? 1.0f : 0.0f) + PD_EPS);
        }
    }
    const float PE = blockSum(pe, red);
    if (t == 0) {
        peld[r] = PE;
        pelp[r] = m + logf(Z) - sdiag;
    }
}

// ---------------- deterministic two-stage f64 reduction ----------------
__global__ __launch_bounds__(1024)
void reduce_k(const float* __restrict__ peld, const float* __restrict__ pelp,
              float* __restrict__ scalars) {
    __shared__ double red[4][16];
    const int t = threadIdx.x;
    double a = 0.0, b = 0.0, c = 0.0, d = 0.0;
    for (int i = t; i < KSEL; i += 1024) {
        const double pd = (double)peld[i];
        const double pp = (double)pelp[i];
        a += pd; b += pd * pd; c += pp; d += pp * pp;
    }
    #pragma unroll
    for (int o = 32; o > 0; o >>= 1) {
        a += __shfl_down(a, o); b += __shfl_down(b, o);
        c += __shfl_down(c, o); d += __shfl_down(d, o);
    }
    const int wv = t >> 6;
    if ((t & 63) == 0) { red[0][wv] = a; red[1][wv] = b; red[2][wv] = c; red[3][wv] = d; }
    __syncthreads();
    if (t == 0) {
        double s1 = 0, s2 = 0, s3 = 0, s4 = 0;
        #pragma unroll
        for (int i = 0; i < 16; ++i) { s1 += red[0][i]; s2 += red[1][i]; s3 += red[2][i]; s4 += red[3][i]; }
        const double Kd = (double)KSEL;
        const double denom = Kd + 1e-5;
        scalars[0] = (float)(s1 / denom);
        scalars[1] = (float)(s3 / denom);
        scalars[2] = (float)((s2 - s1 * s1 / Kd) / (Kd - 1.0));
        scalars[3] = (float)((s4 - s3 * s3 / Kd) / (Kd - 1.0));
    }
}

extern "C" void kernel_launch(void* const* d_in, const int* in_sizes, int n_in,
                              void* d_out, int out_size, void* d_ws, size_t ws_size,
                              hipStream_t stream) {
    const float* msp   = (const float*)d_in[0];
    const float* lab   = (const float*)d_in[1];
    const void*  mask  = d_in[2];
    const float* W     = (const float*)d_in[3];
    const float* bias  = (const float*)d_in[4];
    const float* gamma = (const float*)d_in[5];
    const float* beta  = (const float*)d_in[6];
    float* out = (float*)d_out;
    char*  ws  = (char*)d_ws;

    int*    idx     = (int*)ws;                         // 32 KB
    u16*    wBf     = (u16*)(ws + 65536);               // 2 MB
    u16*    labelsB = (u16*)(ws + (size_t)(4  << 20));  // 16 MB
    u16*    hB      = (u16*)(ws + (size_t)(20 << 20));  // 16 MB
    u16*    predsB  = (u16*)d_out;                      // 16 MB scratch (dead before GEMM2)
    float*  hPre    = out + ((size_t)8 << 20);          // 32 MB scratch (dead before GEMM2)

    float* peld    = out + (size_t)KSEL * KSEL;
    float* pelp    = peld + KSEL;
    float* scalars = pelp + KSEL;

    hipFuncSetAttribute((const void*)gemm256_k,
                        hipFuncAttributeMaxDynamicSharedMemorySize, 163840);

    compact_mask_k<<<1, 1024, 0, stream>>>((const uint8_t*)mask, (const int32_t*)mask, idx);
    convert_w_k<<<(HD * HD) / 1024, 256, 0, stream>>>(W, wBf);
    gather_k<<<KSEL, 256, 0, stream>>>(msp, lab, idx, predsB, labelsB);
    gemm256_k<<<(KSEL / 256) * (HD / 256), 512, 163840, stream>>>(predsB, wBf, hPre, KSEL, HD, HD);
    ln_k<<<KSEL, 256, 0, stream>>>(hPre, bias, gamma, beta, hB);
    gemm256_k<<<(KSEL / 256) * (KSEL / 256), 512, 163840, stream>>>(hB, labelsB, out, KSEL, KSEL, HD);
    softmax_loss_k<<<KSEL, 256, 0, stream>>>(out, peld, pelp);
    reduce_k<<<1, 1024, 0, stream>>>(peld, pelp, scalars);
}